// Round 1
// baseline (93301.819 us; speedup 1.0000x reference)
//
#include <hip/hip_runtime.h>
#include <math.h>

namespace {

constexpr int cH  = 1024;
constexpr int cZ  = 256;
constexpr int cB  = 64;
constexpr int cT  = 256;
constexpr int cR  = 389;
constexpr int cSC = 89;
constexpr int cPF = 300;
constexpr int cIN0 = 645;              // PERF + SCORE + Z
constexpr int ISTR = 648;              // padded layer-0 input stride (floats), 16B aligned
constexpr float INV_S = 0.9999950000374997f;  // 1/sqrt(1+1e-5)

__device__ __forceinline__ void fma4(float4& a, const float4 x, const float4 w){
  a.x = fmaf(x.x, w.x, a.x);
  a.y = fmaf(x.y, w.y, a.y);
  a.z = fmaf(x.z, w.z, a.z);
  a.w = fmaf(x.w, w.w, a.w);
}
__device__ __forceinline__ float fold4(const float4 a){ return (a.x + a.y) + (a.z + a.w); }
__device__ __forceinline__ float4 z4(){ return make_float4(0.f, 0.f, 0.f, 0.f); }
__device__ __forceinline__ float sigm(float x){ return 1.f / (1.f + expf(-x)); }

// ---------------------------------------------------------------- init / prep
__global__ __launch_bounds__(256) void init_kernel(float* hf0, float* hb0, float* dout_tail){
  const int idx = blockIdx.x * 256 + threadIdx.x;
  const int stride = gridDim.x * 256;
  for (int i = idx; i < cB * cH; i += stride){ hf0[i] = 0.f; hb0[i] = 0.f; }
  for (int i = idx; i < 2 * cB * cZ; i += stride) dout_tail[i] = 0.f;
}

__global__ __launch_bounds__(256) void pad_w0_kernel(const float* __restrict__ w,
                                                     float* __restrict__ wp){
  const int idx = blockIdx.x * 256 + threadIdx.x;
  const int stride = gridDim.x * 256;
  const int n = 3 * cH * ISTR;
  for (int i = idx; i < n; i += stride){
    const int r = i / ISTR;
    const int c = i - r * ISTR;
    wp[i] = (c < cIN0) ? w[(size_t)r * cIN0 + c] : 0.f;
  }
}

// ---------------------------------------------------------------- encoder step
// grid (128, 2, 2): kblock, bhalf, dir.  block 256 = 4 d-segments x 64 lanes.
__global__ __launch_bounds__(256) void enc_step_kernel(
    const float* __restrict__ x, int t,
    const float* __restrict__ wih_f, const float* __restrict__ whh_f,
    const float* __restrict__ bih_f, const float* __restrict__ bhh_f,
    const float* __restrict__ hf_in, float* __restrict__ hf_out,
    const float* __restrict__ wih_b, const float* __restrict__ whh_b,
    const float* __restrict__ bih_b, const float* __restrict__ bhh_b,
    const float* __restrict__ hb_in, float* __restrict__ hb_out)
{
  const int dir = blockIdx.z;
  const float* wih = dir ? wih_b : wih_f;
  const float* whh = dir ? whh_b : whh_f;
  const float* bih = dir ? bih_b : bih_f;
  const float* bhh = dir ? bhh_b : bhh_f;
  const float* hin = dir ? hb_in : hf_in;
  float*      hout = dir ? hb_out : hf_out;
  const int tt = dir ? (cT - 1 - t) : t;
  const float* xin = x + (size_t)tt * cB * cR;

  const int tid  = threadIdx.x;
  const int seg  = tid >> 6;
  const int lane = tid & 63;
  const int tx   = lane & 7;
  const int ty   = lane >> 3;
  const int k0    = blockIdx.x * 8;
  const int bbase = blockIdx.y * 32;
  const int k  = k0 + ty;
  const int b0 = bbase + tx * 4;

  float ar[4]  = {0.f,0.f,0.f,0.f};
  float az[4]  = {0.f,0.f,0.f,0.f};
  float ani[4] = {0.f,0.f,0.f,0.f};

  // phase 1: x @ w_ih^T  (scalar: 389-float rows are not 16B aligned)
  {
    const float* wr_row = wih + (size_t)k * cR;
    const float* wz_row = wih + (size_t)(cH + k) * cR;
    const float* wn_row = wih + (size_t)(2 * cH + k) * cR;
    const float* x0 = xin + (size_t)b0 * cR;
    const int q  = 98;                       // ceil(389/4)
    const int d0 = seg * q;
    const int d1 = (d0 + q < cR) ? (d0 + q) : cR;
    #pragma unroll 2
    for (int d = d0; d < d1; ++d){
      const float wr = wr_row[d], wz = wz_row[d], wn = wn_row[d];
      float a[4];
      #pragma unroll
      for (int j = 0; j < 4; ++j) a[j] = x0[(size_t)j * cR + d];
      #pragma unroll
      for (int j = 0; j < 4; ++j){
        ar[j]  = fmaf(a[j], wr, ar[j]);
        az[j]  = fmaf(a[j], wz, az[j]);
        ani[j] = fmaf(a[j], wn, ani[j]);
      }
    }
  }

  // phase 2: h @ w_hh^T  (float4)
  float4 fr[4], fz[4], fnh[4];
  #pragma unroll
  for (int j = 0; j < 4; ++j){ fr[j] = z4(); fz[j] = z4(); fnh[j] = z4(); }
  {
    const float4* h4  = (const float4*)hin;
    const float4* whr = (const float4*)whh + (size_t)k * (cH / 4);
    const float4* whz = (const float4*)whh + (size_t)(cH + k) * (cH / 4);
    const float4* whn = (const float4*)whh + (size_t)(2 * cH + k) * (cH / 4);
    const int q4  = (cH / 4) / 4;            // 64
    const int d40 = seg * q4;
    const int d41 = d40 + q4;
    #pragma unroll 2
    for (int d4 = d40; d4 < d41; ++d4){
      const float4 wr = whr[d4], wz = whz[d4], wn = whn[d4];
      #pragma unroll
      for (int j = 0; j < 4; ++j){
        const float4 a = h4[(size_t)(b0 + j) * (cH / 4) + d4];
        fma4(fr[j], a, wr); fma4(fz[j], a, wz); fma4(fnh[j], a, wn);
      }
    }
  }

  __shared__ float part[4][4][8][32];
  #pragma unroll
  for (int j = 0; j < 4; ++j){
    const int bl = tx * 4 + j;
    part[seg][0][ty][bl] = ar[j] + fold4(fr[j]);
    part[seg][1][ty][bl] = az[j] + fold4(fz[j]);
    part[seg][2][ty][bl] = ani[j];
    part[seg][3][ty][bl] = fold4(fnh[j]);
  }
  __syncthreads();
  {
    const int ke = tid >> 5, bl = tid & 31;
    float rs = 0.f, zs = 0.f, nis = 0.f, nhs = 0.f;
    #pragma unroll
    for (int s = 0; s < 4; ++s){
      rs  += part[s][0][ke][bl];
      zs  += part[s][1][ke][bl];
      nis += part[s][2][ke][bl];
      nhs += part[s][3][ke][bl];
    }
    const int kk = k0 + ke, bb = bbase + bl;
    const float r  = sigm(rs + bih[kk] + bhh[kk]);
    const float zg = sigm(zs + bih[cH + kk] + bhh[cH + kk]);
    const float nn = tanhf(nis + bih[2 * cH + kk] + r * (nhs + bhh[2 * cH + kk]));
    const float hp = hin[(size_t)bb * cH + kk];
    hout[(size_t)bb * cH + kk] = (1.f - zg) * nn + zg * hp;
  }
}

// ---------------------------------------------------------------- decoder GRU step
// grid (128, 2): kblock, bhalf.  All operands 16B aligned (layer0 uses padded W/in).
__global__ __launch_bounds__(256) void dec_gru_kernel(
    const float* __restrict__ in, int inLf4,
    const float* __restrict__ hprev,
    const float* __restrict__ wih, const float* __restrict__ whh,
    const float* __restrict__ bih, const float* __restrict__ bhh,
    float* __restrict__ hout)
{
  const int tid  = threadIdx.x;
  const int seg  = tid >> 6;
  const int lane = tid & 63;
  const int tx   = lane & 7;
  const int ty   = lane >> 3;
  const int k0    = blockIdx.x * 8;
  const int bbase = blockIdx.y * 32;
  const int k  = k0 + ty;
  const int b0 = bbase + tx * 4;

  float4 fr[4], fz[4], fni[4], fnh[4];
  #pragma unroll
  for (int j = 0; j < 4; ++j){ fr[j] = z4(); fz[j] = z4(); fni[j] = z4(); fnh[j] = z4(); }

  // phase 1: in @ w_ih^T
  {
    const float4* in4 = (const float4*)in;
    const float4* wir = (const float4*)wih + (size_t)k * inLf4;
    const float4* wiz = (const float4*)wih + (size_t)(cH + k) * inLf4;
    const float4* win = (const float4*)wih + (size_t)(2 * cH + k) * inLf4;
    const int q4 = (inLf4 + 3) >> 2;
    const int d0 = seg * q4;
    const int d1 = (d0 + q4 < inLf4) ? (d0 + q4) : inLf4;
    #pragma unroll 2
    for (int d4 = d0; d4 < d1; ++d4){
      const float4 wr = wir[d4], wz = wiz[d4], wn = win[d4];
      #pragma unroll
      for (int j = 0; j < 4; ++j){
        const float4 a = in4[(size_t)(b0 + j) * inLf4 + d4];
        fma4(fr[j], a, wr); fma4(fz[j], a, wz); fma4(fni[j], a, wn);
      }
    }
  }
  // phase 2: hprev @ w_hh^T
  {
    const float4* h4  = (const float4*)hprev;
    const float4* whr = (const float4*)whh + (size_t)k * (cH / 4);
    const float4* whz = (const float4*)whh + (size_t)(cH + k) * (cH / 4);
    const float4* whn = (const float4*)whh + (size_t)(2 * cH + k) * (cH / 4);
    const int q4  = (cH / 4) / 4;
    const int d40 = seg * q4;
    const int d41 = d40 + q4;
    #pragma unroll 2
    for (int d4 = d40; d4 < d41; ++d4){
      const float4 wr = whr[d4], wz = whz[d4], wn = whn[d4];
      #pragma unroll
      for (int j = 0; j < 4; ++j){
        const float4 a = h4[(size_t)(b0 + j) * (cH / 4) + d4];
        fma4(fr[j], a, wr); fma4(fz[j], a, wz); fma4(fnh[j], a, wn);
      }
    }
  }

  __shared__ float part[4][4][8][32];
  #pragma unroll
  for (int j = 0; j < 4; ++j){
    const int bl = tx * 4 + j;
    part[seg][0][ty][bl] = fold4(fr[j]);
    part[seg][1][ty][bl] = fold4(fz[j]);
    part[seg][2][ty][bl] = fold4(fni[j]);
    part[seg][3][ty][bl] = fold4(fnh[j]);
  }
  __syncthreads();
  {
    const int ke = tid >> 5, bl = tid & 31;
    float rs = 0.f, zs = 0.f, nis = 0.f, nhs = 0.f;
    #pragma unroll
    for (int s = 0; s < 4; ++s){
      rs  += part[s][0][ke][bl];
      zs  += part[s][1][ke][bl];
      nis += part[s][2][ke][bl];
      nhs += part[s][3][ke][bl];
    }
    const int kk = k0 + ke, bb = bbase + bl;
    const float r  = sigm(rs + bih[kk] + bhh[kk]);
    const float zg = sigm(zs + bih[cH + kk] + bhh[cH + kk]);
    const float nn = tanhf(nis + bih[2 * cH + kk] + r * (nhs + bhh[2 * cH + kk]));
    const float hp = hprev[(size_t)bb * cH + kk];
    hout[(size_t)bb * cH + kk] = (1.f - zg) * nn + zg * hp;
  }
}

// ---------------------------------------------------------------- latent / init of decoder
__global__ __launch_bounds__(256) void latent_kernel(
    const float* __restrict__ hf, const float* __restrict__ hb,
    const float* __restrict__ w_mu, const float* __restrict__ b_mu,
    float* __restrict__ zout)
{
  const int b = blockIdx.x;
  const int tid = threadIdx.x;
  __shared__ alignas(16) float hl[2 * cH];
  ((float4*)hl)[tid]       = ((const float4*)(hf + (size_t)b * cH))[tid];
  ((float4*)hl)[256 + tid] = ((const float4*)(hb + (size_t)b * cH))[tid];
  __syncthreads();
  const float4* h4 = (const float4*)hl;
  const float4* wr = (const float4*)(w_mu + (size_t)tid * 2 * cH);
  float4 s4 = z4();
  #pragma unroll 4
  for (int i = 0; i < 512; ++i) fma4(s4, h4[i], wr[i]);
  zout[(size_t)b * cZ + tid] = b_mu[tid] + fold4(s4) * INV_S;
}

__global__ __launch_bounds__(256) void hinit_kernel(
    const float* __restrict__ zb, const float* __restrict__ w_init,
    const float* __restrict__ b_init, float* __restrict__ h0out)
{
  const int b = blockIdx.x;
  const int tid = threadIdx.x;
  __shared__ alignas(16) float zl[cZ];
  if (tid < 64) ((float4*)zl)[tid] = ((const float4*)(zb + (size_t)b * cZ))[tid];
  __syncthreads();
  const float4* zv = (const float4*)zl;
  for (int kk = tid; kk < cH; kk += 256){
    const float4* wr = (const float4*)(w_init + (size_t)kk * cZ);
    float4 s4 = z4();
    #pragma unroll 4
    for (int i = 0; i < 64; ++i) fma4(s4, zv[i], wr[i]);
    h0out[(size_t)b * cH + kk] = tanhf(b_init[kk] + fold4(s4));
  }
}

__global__ __launch_bounds__(256) void inp_init_kernel(const float* __restrict__ zb,
                                                       float* __restrict__ inp){
  const int b = blockIdx.x;
  for (int c = threadIdx.x; c < ISTR; c += 256){
    float v;
    if (c < cPF)            v = (c == cPF - 1) ? 1.f : 0.f;
    else if (c < cPF + cSC) v = (c == cPF + cSC - 1) ? 1.f : 0.f;
    else if (c < cIN0)      v = zb[(size_t)b * cZ + (c - (cPF + cSC))];
    else                    v = 0.f;
    inp[(size_t)b * ISTR + c] = v;
  }
}

// ---------------------------------------------------------------- decoder output step
// logits + 3x log_softmax + argmax + build next input.  grid = 64 (one block per batch row)
__global__ __launch_bounds__(256) void out_step_kernel(
    const float* __restrict__ hx2, const float* __restrict__ w_out,
    const float* __restrict__ b_out, const float* __restrict__ x, int j,
    float* __restrict__ dout, float* __restrict__ inp)
{
  const int b = blockIdx.x;
  const int tid = threadIdx.x;
  __shared__ alignas(16) float hl[cH];
  __shared__ float lg[cPF];
  __shared__ float gmax[3], glse[3];
  __shared__ float wbest[4];
  __shared__ int   wbidx[4];
  __shared__ int   amax_s;

  ((float4*)hl)[tid] = ((const float4*)(hx2 + (size_t)b * cH))[tid];
  __syncthreads();

  const float4* h4 = (const float4*)hl;
  for (int p = tid; p < cPF; p += 256){
    const float4* wr = (const float4*)(w_out + (size_t)p * cH);
    float4 s4 = z4();
    #pragma unroll 4
    for (int i = 0; i < 256; ++i) fma4(s4, h4[i], wr[i]);
    lg[p] = b_out[p] + fold4(s4);
  }
  __syncthreads();

  const int w = tid >> 6, l = tid & 63;
  if (w < 3){
    float m = -INFINITY;
    for (int p = w * 100 + l; p < w * 100 + 100; p += 64) m = fmaxf(m, lg[p]);
    #pragma unroll
    for (int off = 32; off > 0; off >>= 1) m = fmaxf(m, __shfl_xor(m, off));
    float s = 0.f;
    for (int p = w * 100 + l; p < w * 100 + 100; p += 64) s += expf(lg[p] - m);
    #pragma unroll
    for (int off = 32; off > 0; off >>= 1) s += __shfl_xor(s, off);
    if (l == 0){ gmax[w] = m; glse[w] = logf(s); }
  }
  __syncthreads();

  float best = -INFINITY; int bidx = 0x7fffffff;
  for (int p = tid; p < cPF; p += 256){
    const int g = (p >= 200) ? 2 : ((p >= 100) ? 1 : 0);
    const float o = lg[p] - gmax[g] - glse[g];
    dout[((size_t)b * cT + j) * cPF + p] = o;
    if (o > best || (o == best && p < bidx)){ best = o; bidx = p; }
  }
  #pragma unroll
  for (int off = 32; off > 0; off >>= 1){
    const float ob = __shfl_xor(best, off);
    const int   oi = __shfl_xor(bidx, off);
    if (ob > best || (ob == best && oi < bidx)){ best = ob; bidx = oi; }
  }
  if (l == 0){ wbest[w] = best; wbidx[w] = bidx; }
  __syncthreads();
  if (tid == 0){
    float bb = wbest[0]; int bi = wbidx[0];
    #pragma unroll
    for (int q = 1; q < 4; ++q)
      if (wbest[q] > bb || (wbest[q] == bb && wbidx[q] < bi)){ bb = wbest[q]; bi = wbidx[q]; }
    amax_s = bi;
  }
  __syncthreads();

  const int am = amax_s;
  for (int p = tid; p < cPF; p += 256) inp[(size_t)b * ISTR + p] = (p == am) ? 1.f : 0.f;
  if (tid < cSC) inp[(size_t)b * ISTR + cPF + tid] = x[((size_t)j * cB + b) * cR + tid];
}

} // namespace

// ---------------------------------------------------------------- host
extern "C" void kernel_launch(void* const* d_in, const int* in_sizes, int n_in,
                              void* d_out, int out_size, void* d_ws, size_t ws_size,
                              hipStream_t stream)
{
  const float* x     = (const float*)d_in[0];
  const float* wih_f = (const float*)d_in[2];
  const float* whh_f = (const float*)d_in[3];
  const float* bih_f = (const float*)d_in[4];
  const float* bhh_f = (const float*)d_in[5];
  const float* wih_b = (const float*)d_in[6];
  const float* whh_b = (const float*)d_in[7];
  const float* bih_b = (const float*)d_in[8];
  const float* bhh_b = (const float*)d_in[9];
  const float* w_mu  = (const float*)d_in[10];
  const float* b_mu  = (const float*)d_in[11];
  const float* w_init= (const float*)d_in[14];
  const float* b_init= (const float*)d_in[15];
  const float* w_ih0 = (const float*)d_in[16];
  const float* w_hh0 = (const float*)d_in[17];
  const float* b_ih0 = (const float*)d_in[18];
  const float* b_hh0 = (const float*)d_in[19];
  const float* w_ih1 = (const float*)d_in[20];
  const float* w_hh1 = (const float*)d_in[21];
  const float* b_ih1 = (const float*)d_in[22];
  const float* b_hh1 = (const float*)d_in[23];
  const float* w_ih2 = (const float*)d_in[24];
  const float* w_hh2 = (const float*)d_in[25];
  const float* b_ih2 = (const float*)d_in[26];
  const float* b_hh2 = (const float*)d_in[27];
  const float* w_out = (const float*)d_in[28];
  const float* b_out = (const float*)d_in[29];
  float* dout = (float*)d_out;

  float* ws = (float*)d_ws;
  float* wp0 = ws;                       ws += (size_t)3 * cH * ISTR;   // padded w_ih0
  float* hf[2] = { ws, ws + cB * cH };   ws += 2 * cB * cH;
  float* hb[2] = { ws, ws + cB * cH };   ws += 2 * cB * cH;
  float* h0[2] = { ws, ws + cB * cH };   ws += 2 * cB * cH;
  float* h1[2] = { ws, ws + cB * cH };   ws += 2 * cB * cH;
  float* h2[2] = { ws, ws + cB * cH };   ws += 2 * cB * cH;
  float* zbuf  = ws;                     ws += cB * cZ;
  float* inp   = ws;                     ws += cB * ISTR;

  init_kernel<<<256, 256, 0, stream>>>(hf[0], hb[0], dout + (size_t)cB * cT * cPF);
  pad_w0_kernel<<<512, 256, 0, stream>>>(w_ih0, wp0);

  const dim3 egrid(128, 2, 2);
  for (int t = 0; t < cT; ++t){
    const int cur = t & 1;
    enc_step_kernel<<<egrid, 256, 0, stream>>>(
        x, t,
        wih_f, whh_f, bih_f, bhh_f, hf[cur], hf[cur ^ 1],
        wih_b, whh_b, bih_b, bhh_b, hb[cur], hb[cur ^ 1]);
  }

  latent_kernel<<<cB, 256, 0, stream>>>(hf[0], hb[0], w_mu, b_mu, zbuf);
  hinit_kernel<<<cB, 256, 0, stream>>>(zbuf, w_init, b_init, h0[0]);
  inp_init_kernel<<<cB, 256, 0, stream>>>(zbuf, inp);

  const dim3 dgrid(128, 2, 1);
  for (int j = 0; j < cT; ++j){
    const int cur = j & 1, nxt = cur ^ 1;
    dec_gru_kernel<<<dgrid, 256, 0, stream>>>(inp, ISTR / 4, h0[cur],
                                              wp0, w_hh0, b_ih0, b_hh0, h0[nxt]);
    dec_gru_kernel<<<dgrid, 256, 0, stream>>>(h0[nxt], cH / 4,
                                              (j == 0 ? h0[nxt] : h1[cur]),
                                              w_ih1, w_hh1, b_ih1, b_hh1, h1[nxt]);
    dec_gru_kernel<<<dgrid, 256, 0, stream>>>(h1[nxt], cH / 4,
                                              (j == 0 ? h1[nxt] : h2[cur]),
                                              w_ih2, w_hh2, b_ih2, b_hh2, h2[nxt]);
    out_step_kernel<<<cB, 256, 0, stream>>>(h2[nxt], w_out, b_out, x, j, dout, inp);
  }
}